// Round 7
// baseline (1655.413 us; speedup 1.0000x reference)
//
#include <hip/hip_runtime.h>
#include <hip/hip_bf16.h>

typedef unsigned int u32;

#define EPS_MSG 1e-7f
#define BN_EPS  1e-5f

// ---- small linear: Y[i*ldY + c] = X[i,:]·W[:,c] (+ B[c]) --------------------
template<int I, int O, bool ADDB>
__global__ void k_lin(const float* __restrict__ X, const float* __restrict__ W,
                      const float* __restrict__ B, float* __restrict__ Y,
                      int ldY, int n) {
  __shared__ float Wl[I * O];
  __shared__ float Bl[O];
  for (int t = threadIdx.x; t < I * O; t += blockDim.x) Wl[t] = W[t];
  if (threadIdx.x < O) Bl[threadIdx.x] = ADDB ? B[threadIdx.x] : 0.f;
  __syncthreads();
  int i = blockIdx.x * blockDim.x + threadIdx.x;
  if (i >= n) return;
  float acc[O];
#pragma unroll
  for (int c = 0; c < O; c++) acc[c] = Bl[c];
  const float4* xp = (const float4*)(X + (size_t)i * I);
  for (int q = 0; q < I / 4; q++) {
    float4 v = xp[q];
#pragma unroll
    for (int c = 0; c < O; c++) acc[c] += v.x * Wl[(4 * q + 0) * O + c];
#pragma unroll
    for (int c = 0; c < O; c++) acc[c] += v.y * Wl[(4 * q + 1) * O + c];
#pragma unroll
    for (int c = 0; c < O; c++) acc[c] += v.z * Wl[(4 * q + 2) * O + c];
#pragma unroll
    for (int c = 0; c < O; c++) acc[c] += v.w * Wl[(4 * q + 3) * O + c];
  }
  float* y = Y + (size_t)i * ldY;
#pragma unroll
  for (int c = 0; c < O; c++) y[c] = acc[c];
}

// ---- GENConv edge pass, d=48: one wave per edge (softmax identity, no max) --
// exact identity: sum(e^(m-mx))*... == sum(e^m·m)/sum(e^m); m in (0, ~10] so
// e^m is safe in f32 (verified bit-equivalent to explicit-max variant r1==r4).
__global__ void k_edge48(const int* __restrict__ ei, const float* __restrict__ ea,
                         const float* __restrict__ we, const float* __restrict__ be,
                         const float* __restrict__ h, float* __restrict__ den,
                         float* __restrict__ num, int E) {
  int lane = threadIdx.x & 63;
  int w    = (blockIdx.x * blockDim.x + threadIdx.x) >> 6;
  int nw   = (gridDim.x * blockDim.x) >> 6;
  float wc[16];
#pragma unroll
  for (int k = 0; k < 16; k++) wc[k] = 0.f;
  float bias = 0.f;
  if (lane < 48) {
#pragma unroll
    for (int k = 0; k < 16; k++) wc[k] = we[k * 48 + lane];
    bias = be[lane];
  }
  for (int e = w; e < E; e += nw) {
    int s = ei[e];
    int d = ei[E + e];
    const float4* p = (const float4*)(ea + (size_t)e * 16);
    float ml = bias;
#pragma unroll
    for (int j = 0; j < 4; j++) {
      float4 v = p[j];
      ml += v.x * wc[4 * j + 0] + v.y * wc[4 * j + 1] +
            v.z * wc[4 * j + 2] + v.w * wc[4 * j + 3];
    }
    if (lane < 48) {
      float m  = fmaxf(h[(size_t)s * 48 + lane] + ml, 0.f) + EPS_MSG;
      float ex = __expf(m);
      unsafeAtomicAdd(&den[(size_t)d * 48 + lane], ex);
      unsafeAtomicAdd(&num[(size_t)d * 48 + lane], ex * m);
    }
  }
}

// ---- GENConv edge pass, d=32: half-wave per edge ----------------------------
__global__ void k_edge32(const int* __restrict__ ei, const float* __restrict__ ea,
                         const float* __restrict__ we, const float* __restrict__ be,
                         const float* __restrict__ h, float* __restrict__ den,
                         float* __restrict__ num, int E) {
  int c   = threadIdx.x & 31;
  int hw  = (blockIdx.x * blockDim.x + threadIdx.x) >> 5;
  int nhw = (gridDim.x * blockDim.x) >> 5;
  float wc[16];
#pragma unroll
  for (int k = 0; k < 16; k++) wc[k] = we[k * 32 + c];
  float bias = be[c];
  for (int e = hw; e < E; e += nhw) {
    int s = ei[e], d = ei[E + e];
    const float4* p = (const float4*)(ea + (size_t)e * 16);
    float ml = bias;
#pragma unroll
    for (int j = 0; j < 4; j++) {
      float4 v = p[j];
      ml += v.x * wc[4 * j + 0] + v.y * wc[4 * j + 1] +
            v.z * wc[4 * j + 2] + v.w * wc[4 * j + 3];
    }
    float m  = fmaxf(h[(size_t)s * 32 + c] + ml, 0.f) + EPS_MSG;
    float ex = __expf(m);
    unsafeAtomicAdd(&den[(size_t)d * 32 + c], ex);
    unsafeAtomicAdd(&num[(size_t)d * 32 + c], ex * m);
  }
}

// ---- in-degree --------------------------------------------------------------
__global__ void k_deg(const int* __restrict__ ei, u32* __restrict__ deg, int E) {
  int e = blockIdx.x * blockDim.x + threadIdx.x;
  if (e < E) atomicAdd(&deg[ei[E + e]], 1u);
}

// ---- residual: h += num/(den + 1e-16) ---------------------------------------
__global__ void k_resid(float* __restrict__ h, const float* __restrict__ den,
                        const float* __restrict__ num, size_t total) {
  size_t i = (size_t)blockIdx.x * blockDim.x + threadIdx.x;
  if (i < total) h[i] += num[i] / (den[i] + 1e-16f);
}

// ---- zt = X@W1 + B1, split into two D-wide panels ---------------------------
template<int D>
__global__ void k_zt(const float* __restrict__ X, const float* __restrict__ W,
                     const float* __restrict__ B, float* __restrict__ Z1,
                     float* __restrict__ Z2, int n) {
  __shared__ float Wl[D * 2 * D];
  __shared__ float Bl[2 * D];
  for (int t = threadIdx.x; t < D * 2 * D; t += blockDim.x) Wl[t] = W[t];
  for (int t = threadIdx.x; t < 2 * D; t += blockDim.x) Bl[t] = B[t];
  __syncthreads();
  int i = blockIdx.x * blockDim.x + threadIdx.x;
  if (i >= n) return;
  float acc[2 * D];
#pragma unroll
  for (int c = 0; c < 2 * D; c++) acc[c] = Bl[c];
  const float4* xp = (const float4*)(X + (size_t)i * D);
  for (int q = 0; q < D / 4; q++) {
    float4 v = xp[q];
#pragma unroll
    for (int c = 0; c < 2 * D; c++) acc[c] += v.x * Wl[(4 * q + 0) * 2 * D + c];
#pragma unroll
    for (int c = 0; c < 2 * D; c++) acc[c] += v.y * Wl[(4 * q + 1) * 2 * D + c];
#pragma unroll
    for (int c = 0; c < 2 * D; c++) acc[c] += v.z * Wl[(4 * q + 2) * 2 * D + c];
#pragma unroll
    for (int c = 0; c < 2 * D; c++) acc[c] += v.w * Wl[(4 * q + 3) * 2 * D + c];
  }
  float* z1 = Z1 + (size_t)i * D;
  float* z2 = Z2 + (size_t)i * D;
#pragma unroll
  for (int c = 0; c < D; c++) { z1[c] = acc[c]; z2[c] = acc[D + c]; }
}

// ---- BN stats, deterministic: block c owns channel c ------------------------
template<int D>
__global__ void k_bnstats(const float* __restrict__ Z1, const float* __restrict__ Z2,
                          float* __restrict__ stats, int n) {
  int c = blockIdx.x;
  const float* Z = (c < D) ? Z1 : Z2;
  int cc = (c < D) ? c : c - D;
  float s = 0.f, q = 0.f;
  for (int i = threadIdx.x; i < n; i += blockDim.x) {
    float v = Z[(size_t)i * D + cc];
    s += v; q += v * v;
  }
  __shared__ float rs[256], rq[256];
  int t = threadIdx.x;
  rs[t] = s; rq[t] = q;
  __syncthreads();
  for (int o = 128; o; o >>= 1) {
    if (t < o) { rs[t] += rs[t + o]; rq[t] += rq[t + o]; }
    __syncthreads();
  }
  if (t == 0) { stats[c] = rs[0]; stats[2 * D + c] = rq[0]; }
}

// ---- BN-normalize -> relu -> @W2+b2 -> outer relu ---------------------------
template<int D, int DD>
__global__ void k_mlp_b(const float* __restrict__ ztA, const float* __restrict__ ztB,
                        const float* __restrict__ stats,
                        const float* __restrict__ G, const float* __restrict__ BE,
                        const float* __restrict__ W2, const float* __restrict__ B2,
                        float* __restrict__ out, float invN, int n) {
  __shared__ float Wl[DD * D];
  __shared__ float Bl[D];
  __shared__ float sc[DD], sh[DD];
  for (int t = threadIdx.x; t < DD * D; t += blockDim.x) Wl[t] = W2[t];
  if (threadIdx.x < D) Bl[threadIdx.x] = B2[threadIdx.x];
  if (threadIdx.x < DD) {
    int c   = threadIdx.x;
    float m = stats[c] * invN;
    float v = stats[DD + c] * invN - m * m;
    float s = G[c] * rsqrtf(v + BN_EPS);
    sc[c] = s; sh[c] = BE[c] - m * s;
  }
  __syncthreads();
  int i = blockIdx.x * blockDim.x + threadIdx.x;
  if (i >= n) return;
  float acc[D];
#pragma unroll
  for (int c = 0; c < D; c++) acc[c] = Bl[c];
  const float* a = ztA + (size_t)i * D;
  const float* b = ztB + (size_t)i * D;
  for (int k = 0; k < D; k++) {
    float z = fmaxf(a[k] * sc[k] + sh[k], 0.f);
#pragma unroll
    for (int c = 0; c < D; c++) acc[c] += z * Wl[k * D + c];
  }
  for (int k = D; k < DD; k++) {
    float z = fmaxf(b[k - D] * sc[k] + sh[k], 0.f);
#pragma unroll
    for (int c = 0; c < D; c++) acc[c] += z * Wl[k * D + c];
  }
  float* y = out + (size_t)i * D;
#pragma unroll
  for (int c = 0; c < D; c++) y[c] = fmaxf(acc[c], 0.f);
}

// ---- GCN heads ---------------------------------------------------------------
__global__ void k_dinv(const u32* __restrict__ deg, float* __restrict__ dinv, int n) {
  int i = blockIdx.x * blockDim.x + threadIdx.x;
  if (i < n) dinv[i] = rsqrtf((float)(deg[i] + 1u));
}

__global__ void k_hinit(const float* __restrict__ yz, const float* __restrict__ dinv,
                        const float* __restrict__ bmu, const float* __restrict__ bls,
                        float* __restrict__ acc, int n) {
  int idx = blockIdx.x * blockDim.x + threadIdx.x;
  if (idx >= n * 32) return;
  int i = idx >> 5, c = idx & 31;
  float dv   = dinv[i];
  float bias = (c < 16) ? bmu[c] : bls[c - 16];
  acc[idx] = yz[idx] * dv * dv + bias;
}

__global__ void k_hedge(const int* __restrict__ ei, const float* __restrict__ yz,
                        const float* __restrict__ dinv, float* acc, int E) {
  int c   = threadIdx.x & 31;
  int hw  = (blockIdx.x * blockDim.x + threadIdx.x) >> 5;
  int nhw = (gridDim.x * blockDim.x) >> 5;
  for (int e = hw; e < E; e += nhw) {
    int s = ei[e], d = ei[E + e];
    float nrm = dinv[s] * dinv[d];
    unsafeAtomicAdd(&acc[(size_t)d * 32 + c], yz[(size_t)s * 32 + c] * nrm);
  }
}

// d_out is FLOAT32 (r6 diagnosis): mu block [0, N*16), logstd [N*16, N*32)
__global__ void k_store(const float* __restrict__ acc, float* __restrict__ out, int n) {
  int idx = blockIdx.x * blockDim.x + threadIdx.x;
  if (idx >= n * 16) return;
  int i = idx >> 4, c = idx & 15;
  out[idx]          = acc[(size_t)i * 32 + c];
  out[n * 16 + idx] = acc[(size_t)i * 32 + 16 + c];
}

extern "C" void kernel_launch(void* const* d_in, const int* in_sizes, int n_in,
                              void* d_out, int out_size, void* d_ws, size_t ws_size,
                              hipStream_t stream) {
  const float* x      = (const float*)d_in[0];
  const int*  ei      = (const int*)d_in[1];          // int32 (2,E) rows [r5 probe]
  const float* ea     = (const float*)d_in[2];
  const float* w_src1 = (const float*)d_in[3];  const float* b_src1 = (const float*)d_in[4];
  const float* w_edge1= (const float*)d_in[5];  const float* b_edge1= (const float*)d_in[6];
  const float* w_m1a  = (const float*)d_in[7];  const float* b_m1a  = (const float*)d_in[8];
  const float* g1     = (const float*)d_in[9];  const float* be1    = (const float*)d_in[10];
  const float* w_m1b  = (const float*)d_in[11]; const float* b_m1b  = (const float*)d_in[12];
  const float* w_src2 = (const float*)d_in[13]; const float* b_src2 = (const float*)d_in[14];
  const float* w_edge2= (const float*)d_in[15]; const float* b_edge2= (const float*)d_in[16];
  const float* w_m2a  = (const float*)d_in[17]; const float* b_m2a  = (const float*)d_in[18];
  const float* g2     = (const float*)d_in[19]; const float* be2    = (const float*)d_in[20];
  const float* w_m2b  = (const float*)d_in[21]; const float* b_m2b  = (const float*)d_in[22];
  const float* w_mu   = (const float*)d_in[23]; const float* b_mu   = (const float*)d_in[24];
  const float* w_ls   = (const float*)d_in[25]; const float* b_ls   = (const float*)d_in[26];

  const int N = in_sizes[0] / 64;
  const int E = in_sizes[1] / 2;

  float* ws    = (float*)d_ws;
  size_t N48   = (size_t)N * 48;
  float* P0    = ws;                // h / head-linear buffer
  float* P1    = ws + N48;          // den -> ztA -> head acc
  float* P2    = ws + 2 * N48;      // num -> ztB
  float* P3    = ws + 3 * N48;      // layer output
  u32*   deg   = (u32*)(ws + 4 * N48);
  float* dinv  = (float*)(deg + N);
  float* stats = dinv + N;          // 512 floats (L1 at 0, L2 at 256)

  const int NB = (N + 255) / 256;
  const int EB = (E + 255) / 256;
  dim3 b256(256);

  hipMemsetAsync(P1, 0, 2 * N48 * sizeof(float), stream);          // den,num
  hipMemsetAsync(deg, 0, (2 * (size_t)N + 512) * sizeof(u32), stream);

  k_deg<<<EB, b256, 0, stream>>>(ei, deg, E);

  // ---- GENConv 1 (64 -> 48) ----
  k_lin<64, 48, true><<<NB, b256, 0, stream>>>(x, w_src1, b_src1, P0, 48, N);
  k_edge48<<<4096, b256, 0, stream>>>(ei, ea, w_edge1, b_edge1, P0, P1, P2, E);
  k_resid<<<(int)((N48 + 255) / 256), b256, 0, stream>>>(P0, P1, P2, N48);
  k_zt<48><<<NB, b256, 0, stream>>>(P0, w_m1a, b_m1a, P1, P2, N);
  k_bnstats<48><<<96, b256, 0, stream>>>(P1, P2, stats, N);
  k_mlp_b<48, 96><<<NB, b256, 0, stream>>>(P1, P2, stats, g1, be1, w_m1b, b_m1b, P3,
                                           1.0f / (float)N, N);

  // ---- GENConv 2 (48 -> 32) ----
  hipMemsetAsync(P1, 0, 2 * N48 * sizeof(float), stream);
  k_lin<48, 32, true><<<NB, b256, 0, stream>>>(P3, w_src2, b_src2, P0, 32, N);
  k_edge32<<<4096, b256, 0, stream>>>(ei, ea, w_edge2, b_edge2, P0, P1, P2, E);
  k_resid<<<(int)(((size_t)N * 32 + 255) / 256), b256, 0, stream>>>(P0, P1, P2, (size_t)N * 32);
  k_zt<32><<<NB, b256, 0, stream>>>(P0, w_m2a, b_m2a, P1, P2, N);
  k_bnstats<32><<<64, b256, 0, stream>>>(P1, P2, stats + 256, N);
  k_mlp_b<32, 64><<<NB, b256, 0, stream>>>(P1, P2, stats + 256, g2, be2, w_m2b, b_m2b, P3,
                                           1.0f / (float)N, N);

  // ---- GCN heads (32 -> 16 x2) ----
  k_lin<32, 16, false><<<NB, b256, 0, stream>>>(P3, w_mu, nullptr, P0, 32, N);
  k_lin<32, 16, false><<<NB, b256, 0, stream>>>(P3, w_ls, nullptr, P0 + 16, 32, N);
  k_dinv<<<NB, b256, 0, stream>>>(deg, dinv, N);
  k_hinit<<<(N * 32 + 255) / 256, b256, 0, stream>>>(P0, dinv, b_mu, b_ls, P1, N);
  k_hedge<<<4096, b256, 0, stream>>>(ei, P0, dinv, P1, E);
  k_store<<<(N * 16 + 255) / 256, b256, 0, stream>>>(P1, (float*)d_out, N);
}

// Round 8
// 1189.524 us; speedup vs baseline: 1.3917x; 1.3917x over previous
//
#include <hip/hip_runtime.h>
#include <hip/hip_bf16.h>

typedef unsigned int u32;

#define EPS_MSG 1e-7f
#define BN_EPS  1e-5f

// ---- small linear: Y[i*ldY + c] = X[i,:]·W[:,c] (+ B[c]) --------------------
template<int I, int O, bool ADDB>
__global__ void k_lin(const float* __restrict__ X, const float* __restrict__ W,
                      const float* __restrict__ B, float* __restrict__ Y,
                      int ldY, int n) {
  __shared__ float Wl[I * O];
  __shared__ float Bl[O];
  for (int t = threadIdx.x; t < I * O; t += blockDim.x) Wl[t] = W[t];
  if (threadIdx.x < O) Bl[threadIdx.x] = ADDB ? B[threadIdx.x] : 0.f;
  __syncthreads();
  int i = blockIdx.x * blockDim.x + threadIdx.x;
  if (i >= n) return;
  float acc[O];
#pragma unroll
  for (int c = 0; c < O; c++) acc[c] = Bl[c];
  const float4* xp = (const float4*)(X + (size_t)i * I);
  for (int q = 0; q < I / 4; q++) {
    float4 v = xp[q];
#pragma unroll
    for (int c = 0; c < O; c++) acc[c] += v.x * Wl[(4 * q + 0) * O + c];
#pragma unroll
    for (int c = 0; c < O; c++) acc[c] += v.y * Wl[(4 * q + 1) * O + c];
#pragma unroll
    for (int c = 0; c < O; c++) acc[c] += v.z * Wl[(4 * q + 2) * O + c];
#pragma unroll
    for (int c = 0; c < O; c++) acc[c] += v.w * Wl[(4 * q + 3) * O + c];
  }
  float* y = Y + (size_t)i * ldY;
#pragma unroll
  for (int c = 0; c < O; c++) y[c] = acc[c];
}

// ---- CSR construction -------------------------------------------------------
__global__ void k_deg(const int* __restrict__ ei, u32* __restrict__ deg, int E) {
  int e = blockIdx.x * blockDim.x + threadIdx.x;
  if (e < E) atomicAdd(&deg[ei[E + e]], 1u);
}

// block = 256 threads, 1024 elems/block; exclusive scan within block
__global__ void k_scan1(const u32* __restrict__ deg, u32* __restrict__ excl,
                        u32* __restrict__ part, int n) {
  __shared__ u32 sm[256];
  int t = threadIdx.x;
  int base = blockIdx.x * 1024 + t * 4;
  u32 v0 = (base + 0 < n) ? deg[base + 0] : 0u;
  u32 v1 = (base + 1 < n) ? deg[base + 1] : 0u;
  u32 v2 = (base + 2 < n) ? deg[base + 2] : 0u;
  u32 v3 = (base + 3 < n) ? deg[base + 3] : 0u;
  u32 tsum = v0 + v1 + v2 + v3;
  sm[t] = tsum;
  __syncthreads();
  for (int o = 1; o < 256; o <<= 1) {
    u32 v = (t >= o) ? sm[t - o] : 0u;
    __syncthreads();
    sm[t] += v;
    __syncthreads();
  }
  u32 tex = sm[t] - tsum;   // exclusive prefix of this thread's 4-group
  if (t == 255) part[blockIdx.x] = sm[255];
  if (base + 0 < n) excl[base + 0] = tex;
  if (base + 1 < n) excl[base + 1] = tex + v0;
  if (base + 2 < n) excl[base + 2] = tex + v0 + v1;
  if (base + 3 < n) excl[base + 3] = tex + v0 + v1 + v2;
}

__global__ void k_scan2(u32* __restrict__ part, int nb) {
  if (threadIdx.x == 0) {
    u32 acc = 0;
    for (int i = 0; i < nb; i++) { u32 v = part[i]; part[i] = acc; acc += v; }
  }
}

__global__ void k_scan3(u32* __restrict__ rowptr, const u32* __restrict__ part,
                        int n, int E) {
  int i = blockIdx.x * blockDim.x + threadIdx.x;
  if (i < n) rowptr[i] += part[i >> 10];
  if (i == 0) rowptr[n] = (u32)E;
}

__global__ void k_slots(const int* __restrict__ ei, const u32* __restrict__ rowptr,
                        u32* __restrict__ cnt, int* __restrict__ csr_src,
                        int* __restrict__ csr_eid, int E) {
  int e = blockIdx.x * blockDim.x + threadIdx.x;
  if (e >= E) return;
  int s = ei[e], d = ei[E + e];
  u32 slot = rowptr[d] + atomicAdd(&cnt[d], 1u);
  csr_src[slot] = s;
  csr_eid[slot] = e;
}

// ---- GENConv aggregation, d=48: one wave per destination node ---------------
// out[i] = h[i] + (sum e^m * m)/(sum e^m + 1e-16), m = relu(h[src]+edgelin)+eps
__global__ void k_agg48(const u32* __restrict__ rowptr, const int* __restrict__ csr_src,
                        const int* __restrict__ csr_eid, const float* __restrict__ ea,
                        const float* __restrict__ we, const float* __restrict__ be,
                        const float* __restrict__ h, float* __restrict__ out, int n) {
  int lane = threadIdx.x & 63;
  int node = (blockIdx.x * blockDim.x + threadIdx.x) >> 6;
  if (node >= n) return;
  float wc[16];
#pragma unroll
  for (int k = 0; k < 16; k++) wc[k] = 0.f;
  float bias = 0.f;
  if (lane < 48) {
#pragma unroll
    for (int k = 0; k < 16; k++) wc[k] = we[k * 48 + lane];
    bias = be[lane];
  }
  u32 b = rowptr[node], t = rowptr[node + 1];
  float den = 0.f, num = 0.f;
  for (u32 s0 = b; s0 < t; s0++) {
    int e = csr_eid[s0];
    int s = csr_src[s0];
    const float4* p = (const float4*)(ea + (size_t)e * 16);
    float ml = bias;
#pragma unroll
    for (int j = 0; j < 4; j++) {
      float4 v = p[j];
      ml += v.x * wc[4 * j + 0] + v.y * wc[4 * j + 1] +
            v.z * wc[4 * j + 2] + v.w * wc[4 * j + 3];
    }
    if (lane < 48) {
      float m  = fmaxf(h[(size_t)s * 48 + lane] + ml, 0.f) + EPS_MSG;
      float ex = __expf(m);
      den += ex;
      num += ex * m;
    }
  }
  if (lane < 48)
    out[(size_t)node * 48 + lane] = h[(size_t)node * 48 + lane] + num / (den + 1e-16f);
}

// ---- GENConv aggregation, d=32: half-wave per destination node --------------
__global__ void k_agg32(const u32* __restrict__ rowptr, const int* __restrict__ csr_src,
                        const int* __restrict__ csr_eid, const float* __restrict__ ea,
                        const float* __restrict__ we, const float* __restrict__ be,
                        const float* __restrict__ h, float* __restrict__ out, int n) {
  int c    = threadIdx.x & 31;
  int node = (blockIdx.x * blockDim.x + threadIdx.x) >> 5;
  if (node >= n) return;
  float wc[16];
#pragma unroll
  for (int k = 0; k < 16; k++) wc[k] = we[k * 32 + c];
  float bias = be[c];
  u32 b = rowptr[node], t = rowptr[node + 1];
  float den = 0.f, num = 0.f;
  for (u32 s0 = b; s0 < t; s0++) {
    int e = csr_eid[s0];
    int s = csr_src[s0];
    const float4* p = (const float4*)(ea + (size_t)e * 16);
    float ml = bias;
#pragma unroll
    for (int j = 0; j < 4; j++) {
      float4 v = p[j];
      ml += v.x * wc[4 * j + 0] + v.y * wc[4 * j + 1] +
            v.z * wc[4 * j + 2] + v.w * wc[4 * j + 3];
    }
    float m  = fmaxf(h[(size_t)s * 32 + c] + ml, 0.f) + EPS_MSG;
    float ex = __expf(m);
    den += ex;
    num += ex * m;
  }
  out[(size_t)node * 32 + c] = h[(size_t)node * 32 + c] + num / (den + 1e-16f);
}

// ---- zt = X@W1 + B1, split into two D-wide panels ---------------------------
template<int D>
__global__ void k_zt(const float* __restrict__ X, const float* __restrict__ W,
                     const float* __restrict__ B, float* __restrict__ Z1,
                     float* __restrict__ Z2, int n) {
  __shared__ float Wl[D * 2 * D];
  __shared__ float Bl[2 * D];
  for (int t = threadIdx.x; t < D * 2 * D; t += blockDim.x) Wl[t] = W[t];
  for (int t = threadIdx.x; t < 2 * D; t += blockDim.x) Bl[t] = B[t];
  __syncthreads();
  int i = blockIdx.x * blockDim.x + threadIdx.x;
  if (i >= n) return;
  float acc[2 * D];
#pragma unroll
  for (int c = 0; c < 2 * D; c++) acc[c] = Bl[c];
  const float4* xp = (const float4*)(X + (size_t)i * D);
  for (int q = 0; q < D / 4; q++) {
    float4 v = xp[q];
#pragma unroll
    for (int c = 0; c < 2 * D; c++) acc[c] += v.x * Wl[(4 * q + 0) * 2 * D + c];
#pragma unroll
    for (int c = 0; c < 2 * D; c++) acc[c] += v.y * Wl[(4 * q + 1) * 2 * D + c];
#pragma unroll
    for (int c = 0; c < 2 * D; c++) acc[c] += v.z * Wl[(4 * q + 2) * 2 * D + c];
#pragma unroll
    for (int c = 0; c < 2 * D; c++) acc[c] += v.w * Wl[(4 * q + 3) * 2 * D + c];
  }
  float* z1 = Z1 + (size_t)i * D;
  float* z2 = Z2 + (size_t)i * D;
#pragma unroll
  for (int c = 0; c < D; c++) { z1[c] = acc[c]; z2[c] = acc[D + c]; }
}

// ---- BN stats, deterministic: block c owns channel c ------------------------
template<int D>
__global__ void k_bnstats(const float* __restrict__ Z1, const float* __restrict__ Z2,
                          float* __restrict__ stats, int n) {
  int c = blockIdx.x;
  const float* Z = (c < D) ? Z1 : Z2;
  int cc = (c < D) ? c : c - D;
  float s = 0.f, q = 0.f;
  for (int i = threadIdx.x; i < n; i += blockDim.x) {
    float v = Z[(size_t)i * D + cc];
    s += v; q += v * v;
  }
  __shared__ float rs[256], rq[256];
  int t = threadIdx.x;
  rs[t] = s; rq[t] = q;
  __syncthreads();
  for (int o = 128; o; o >>= 1) {
    if (t < o) { rs[t] += rs[t + o]; rq[t] += rq[t + o]; }
    __syncthreads();
  }
  if (t == 0) { stats[c] = rs[0]; stats[2 * D + c] = rq[0]; }
}

// ---- BN-normalize -> relu -> @W2+b2 -> outer relu ---------------------------
template<int D, int DD>
__global__ void k_mlp_b(const float* __restrict__ ztA, const float* __restrict__ ztB,
                        const float* __restrict__ stats,
                        const float* __restrict__ G, const float* __restrict__ BE,
                        const float* __restrict__ W2, const float* __restrict__ B2,
                        float* __restrict__ out, float invN, int n) {
  __shared__ float Wl[DD * D];
  __shared__ float Bl[D];
  __shared__ float sc[DD], sh[DD];
  for (int t = threadIdx.x; t < DD * D; t += blockDim.x) Wl[t] = W2[t];
  if (threadIdx.x < D) Bl[threadIdx.x] = B2[threadIdx.x];
  if (threadIdx.x < DD) {
    int c   = threadIdx.x;
    float m = stats[c] * invN;
    float v = stats[DD + c] * invN - m * m;
    float s = G[c] * rsqrtf(v + BN_EPS);
    sc[c] = s; sh[c] = BE[c] - m * s;
  }
  __syncthreads();
  int i = blockIdx.x * blockDim.x + threadIdx.x;
  if (i >= n) return;
  float acc[D];
#pragma unroll
  for (int c = 0; c < D; c++) acc[c] = Bl[c];
  const float* a = ztA + (size_t)i * D;
  const float* b = ztB + (size_t)i * D;
  for (int k = 0; k < D; k++) {
    float z = fmaxf(a[k] * sc[k] + sh[k], 0.f);
#pragma unroll
    for (int c = 0; c < D; c++) acc[c] += z * Wl[k * D + c];
  }
  for (int k = D; k < DD; k++) {
    float z = fmaxf(b[k - D] * sc[k] + sh[k], 0.f);
#pragma unroll
    for (int c = 0; c < D; c++) acc[c] += z * Wl[k * D + c];
  }
  float* y = out + (size_t)i * D;
#pragma unroll
  for (int c = 0; c < D; c++) y[c] = fmaxf(acc[c], 0.f);
}

// ---- degree-inverse ---------------------------------------------------------
__global__ void k_dinv(const u32* __restrict__ deg, float* __restrict__ dinv, int n) {
  int i = blockIdx.x * blockDim.x + threadIdx.x;
  if (i < n) dinv[i] = rsqrtf((float)(deg[i] + 1u));
}

// ---- GCN heads, CSR gather, fused init+edges+store to d_out -----------------
// out_mu[i][c] = dv*(sum_s yz[s][c]*dinv[s] + yz[i][c]*dv) + b[c]
__global__ void k_gcn(const u32* __restrict__ rowptr, const int* __restrict__ csr_src,
                      const float* __restrict__ yz, const float* __restrict__ dinv,
                      const float* __restrict__ bmu, const float* __restrict__ bls,
                      float* __restrict__ out, int n) {
  int c    = threadIdx.x & 31;
  int node = (blockIdx.x * blockDim.x + threadIdx.x) >> 5;
  if (node >= n) return;
  u32 b = rowptr[node], t = rowptr[node + 1];
  float acc = 0.f;
  for (u32 s0 = b; s0 < t; s0++) {
    int s = csr_src[s0];
    acc += yz[(size_t)s * 32 + c] * dinv[s];
  }
  float dv  = dinv[node];
  float val = (acc + yz[(size_t)node * 32 + c] * dv) * dv +
              ((c < 16) ? bmu[c] : bls[c - 16]);
  if (c < 16) out[(size_t)node * 16 + c] = val;
  else        out[(size_t)n * 16 + (size_t)node * 16 + (c - 16)] = val;
}

extern "C" void kernel_launch(void* const* d_in, const int* in_sizes, int n_in,
                              void* d_out, int out_size, void* d_ws, size_t ws_size,
                              hipStream_t stream) {
  const float* x      = (const float*)d_in[0];
  const int*  ei      = (const int*)d_in[1];          // int32 (2,E) rows
  const float* ea     = (const float*)d_in[2];
  const float* w_src1 = (const float*)d_in[3];  const float* b_src1 = (const float*)d_in[4];
  const float* w_edge1= (const float*)d_in[5];  const float* b_edge1= (const float*)d_in[6];
  const float* w_m1a  = (const float*)d_in[7];  const float* b_m1a  = (const float*)d_in[8];
  const float* g1     = (const float*)d_in[9];  const float* be1    = (const float*)d_in[10];
  const float* w_m1b  = (const float*)d_in[11]; const float* b_m1b  = (const float*)d_in[12];
  const float* w_src2 = (const float*)d_in[13]; const float* b_src2 = (const float*)d_in[14];
  const float* w_edge2= (const float*)d_in[15]; const float* b_edge2= (const float*)d_in[16];
  const float* w_m2a  = (const float*)d_in[17]; const float* b_m2a  = (const float*)d_in[18];
  const float* g2     = (const float*)d_in[19]; const float* be2    = (const float*)d_in[20];
  const float* w_m2b  = (const float*)d_in[21]; const float* b_m2b  = (const float*)d_in[22];
  const float* w_mu   = (const float*)d_in[23]; const float* b_mu   = (const float*)d_in[24];
  const float* w_ls   = (const float*)d_in[25]; const float* b_ls   = (const float*)d_in[26];

  const int N = in_sizes[0] / 64;
  const int E = in_sizes[1] / 2;

  float* ws     = (float*)d_ws;
  size_t N48    = (size_t)N * 48;
  float* P0     = ws;
  float* P1     = ws + N48;
  float* P2     = ws + 2 * N48;
  float* P3     = ws + 3 * N48;
  u32*  rowptr  = (u32*)(ws + 4 * N48);    // N+1
  u32*  cnt     = rowptr + (N + 1);        // N
  u32*  deg     = cnt + N;                 // N
  u32*  part    = deg + N;                 // 256
  float* dinv   = (float*)(part + 256);    // N
  float* stats  = dinv + N;                // 512
  int*  csr_src = (int*)(stats + 512);     // E
  int*  csr_eid = csr_src + E;             // E

  const int NB  = (N + 255) / 256;
  const int EB  = (E + 255) / 256;
  const int SB1 = (N + 1023) / 1024;       // scan blocks
  dim3 b256(256);

  // zero cnt + deg (adjacent)
  hipMemsetAsync(cnt, 0, 2 * (size_t)N * sizeof(u32), stream);

  // CSR build
  k_deg<<<EB, b256, 0, stream>>>(ei, deg, E);
  k_scan1<<<SB1, b256, 0, stream>>>(deg, rowptr, part, N);
  k_scan2<<<1, 64, 0, stream>>>(part, SB1);
  k_scan3<<<NB, b256, 0, stream>>>(rowptr, part, N, E);
  k_slots<<<EB, b256, 0, stream>>>(ei, rowptr, cnt, csr_src, csr_eid, E);
  k_dinv<<<NB, b256, 0, stream>>>(deg, dinv, N);

  // ---- GENConv 1 (64 -> 48) ----
  k_lin<64, 48, true><<<NB, b256, 0, stream>>>(x, w_src1, b_src1, P0, 48, N);
  k_agg48<<<(N * 64 + 255) / 256, b256, 0, stream>>>(rowptr, csr_src, csr_eid, ea,
                                                     w_edge1, b_edge1, P0, P3, N);
  k_zt<48><<<NB, b256, 0, stream>>>(P3, w_m1a, b_m1a, P1, P2, N);
  k_bnstats<48><<<96, b256, 0, stream>>>(P1, P2, stats, N);
  k_mlp_b<48, 96><<<NB, b256, 0, stream>>>(P1, P2, stats, g1, be1, w_m1b, b_m1b, P0,
                                           1.0f / (float)N, N);

  // ---- GENConv 2 (48 -> 32) ----
  k_lin<48, 32, true><<<NB, b256, 0, stream>>>(P0, w_src2, b_src2, P3, 32, N);
  k_agg32<<<(N * 32 + 255) / 256, b256, 0, stream>>>(rowptr, csr_src, csr_eid, ea,
                                                     w_edge2, b_edge2, P3, P0, N);
  k_zt<32><<<NB, b256, 0, stream>>>(P0, w_m2a, b_m2a, P1, P2, N);
  k_bnstats<32><<<64, b256, 0, stream>>>(P1, P2, stats + 256, N);
  k_mlp_b<32, 64><<<NB, b256, 0, stream>>>(P1, P2, stats + 256, g2, be2, w_m2b, b_m2b, P3,
                                           1.0f / (float)N, N);

  // ---- GCN heads (32 -> 16 x2), fused ----
  k_lin<32, 16, false><<<NB, b256, 0, stream>>>(P3, w_mu, nullptr, P0, 32, N);
  k_lin<32, 16, false><<<NB, b256, 0, stream>>>(P3, w_ls, nullptr, P0 + 16, 32, N);
  k_gcn<<<(N * 32 + 255) / 256, b256, 0, stream>>>(rowptr, csr_src, P0, dinv,
                                                   b_mu, b_ls, (float*)d_out, N);
}

// Round 9
// 1158.667 us; speedup vs baseline: 1.4287x; 1.0266x over previous
//
#include <hip/hip_runtime.h>
#include <hip/hip_bf16.h>

typedef unsigned int u32;

#define EPS_MSG 1e-7f
#define BN_EPS  1e-5f

// ---- small linear: Y[i*ldY + c] = X[i,:]·W[:,c] + B[c] ----------------------
template<int I, int O>
__global__ void k_lin(const float* __restrict__ X, const float* __restrict__ W,
                      const float* __restrict__ B, float* __restrict__ Y,
                      int ldY, int n) {
  __shared__ float Wl[I * O];
  __shared__ float Bl[O];
  for (int t = threadIdx.x; t < I * O; t += blockDim.x) Wl[t] = W[t];
  if (threadIdx.x < O) Bl[threadIdx.x] = B[threadIdx.x];
  __syncthreads();
  int i = blockIdx.x * blockDim.x + threadIdx.x;
  if (i >= n) return;
  float acc[O];
#pragma unroll
  for (int c = 0; c < O; c++) acc[c] = Bl[c];
  const float4* xp = (const float4*)(X + (size_t)i * I);
  for (int q = 0; q < I / 4; q++) {
    float4 v = xp[q];
#pragma unroll
    for (int c = 0; c < O; c++) acc[c] += v.x * Wl[(4 * q + 0) * O + c];
#pragma unroll
    for (int c = 0; c < O; c++) acc[c] += v.y * Wl[(4 * q + 1) * O + c];
#pragma unroll
    for (int c = 0; c < O; c++) acc[c] += v.z * Wl[(4 * q + 2) * O + c];
#pragma unroll
    for (int c = 0; c < O; c++) acc[c] += v.w * Wl[(4 * q + 3) * O + c];
  }
  float* y = Y + (size_t)i * ldY;
#pragma unroll
  for (int c = 0; c < O; c++) y[c] = acc[c];
}

// ---- CSR construction -------------------------------------------------------
__global__ void k_deg(const int* __restrict__ ei, u32* __restrict__ deg, int E) {
  int e = blockIdx.x * blockDim.x + threadIdx.x;
  if (e < E) atomicAdd(&deg[ei[E + e]], 1u);
}

__global__ void k_scan1(const u32* __restrict__ deg, u32* __restrict__ excl,
                        u32* __restrict__ part, int n) {
  __shared__ u32 sm[256];
  int t = threadIdx.x;
  int base = blockIdx.x * 1024 + t * 4;
  u32 v0 = (base + 0 < n) ? deg[base + 0] : 0u;
  u32 v1 = (base + 1 < n) ? deg[base + 1] : 0u;
  u32 v2 = (base + 2 < n) ? deg[base + 2] : 0u;
  u32 v3 = (base + 3 < n) ? deg[base + 3] : 0u;
  u32 tsum = v0 + v1 + v2 + v3;
  sm[t] = tsum;
  __syncthreads();
  for (int o = 1; o < 256; o <<= 1) {
    u32 v = (t >= o) ? sm[t - o] : 0u;
    __syncthreads();
    sm[t] += v;
    __syncthreads();
  }
  u32 tex = sm[t] - tsum;
  if (t == 255) part[blockIdx.x] = sm[255];
  if (base + 0 < n) excl[base + 0] = tex;
  if (base + 1 < n) excl[base + 1] = tex + v0;
  if (base + 2 < n) excl[base + 2] = tex + v0 + v1;
  if (base + 3 < n) excl[base + 3] = tex + v0 + v1 + v2;
}

__global__ void k_scan2(u32* __restrict__ part, int nb) {
  if (threadIdx.x == 0) {
    u32 acc = 0;
    for (int i = 0; i < nb; i++) { u32 v = part[i]; part[i] = acc; acc += v; }
  }
}

__global__ void k_scan3(u32* __restrict__ rowptr, const u32* __restrict__ part,
                        int n, int E) {
  int i = blockIdx.x * blockDim.x + threadIdx.x;
  if (i < n) rowptr[i] += part[i >> 10];
  if (i == 0) rowptr[n] = (u32)E;
}

__global__ void k_slots(const int* __restrict__ ei, const u32* __restrict__ rowptr,
                        u32* __restrict__ cnt, int2* __restrict__ csr, int E) {
  int e = blockIdx.x * blockDim.x + threadIdx.x;
  if (e >= E) return;
  int s = ei[e], d = ei[E + e];
  u32 slot = rowptr[d] + atomicAdd(&cnt[d], 1u);
  csr[slot] = make_int2(s, e);
}

__global__ void k_dinv(const u32* __restrict__ deg, float* __restrict__ dinv, int n) {
  int i = blockIdx.x * blockDim.x + threadIdx.x;
  if (i < n) dinv[i] = rsqrtf((float)(deg[i] + 1u));
}

// ---- GENConv aggregation d=48: wave/node, software-pipelined edge loop ------
__global__ void k_agg48(const u32* __restrict__ rowptr, const int2* __restrict__ csr,
                        const float* __restrict__ ea,
                        const float* __restrict__ we, const float* __restrict__ be,
                        const float* __restrict__ h, float* __restrict__ out, int n) {
  int lane = threadIdx.x & 63;
  int node = (blockIdx.x * blockDim.x + threadIdx.x) >> 6;
  if (node >= n) return;
  float wc[16];
#pragma unroll
  for (int k = 0; k < 16; k++) wc[k] = 0.f;
  float bias = 0.f;
  if (lane < 48) {
#pragma unroll
    for (int k = 0; k < 16; k++) wc[k] = we[k * 48 + lane];
    bias = be[lane];
  }
  float hself = (lane < 48) ? h[(size_t)node * 48 + lane] : 0.f;
  u32 b = rowptr[node], t = rowptr[node + 1];
  float den = 0.f, num = 0.f;
  if (b < t) {
    int2 es = csr[b];
    const float4* p = (const float4*)(ea + (size_t)es.y * 16);
    float4 p0 = p[0], p1 = p[1], p2 = p[2], p3 = p[3];
    float hv = (lane < 48) ? h[(size_t)es.x * 48 + lane] : 0.f;
    for (u32 i = b; i < t; i++) {
      float4 q0 = p0, q1 = p1, q2 = p2, q3 = p3;
      float hv0 = hv;
      if (i + 1 < t) {
        int2 es2 = csr[i + 1];
        const float4* pp = (const float4*)(ea + (size_t)es2.y * 16);
        p0 = pp[0]; p1 = pp[1]; p2 = pp[2]; p3 = pp[3];
        hv = (lane < 48) ? h[(size_t)es2.x * 48 + lane] : 0.f;
      }
      float ml = bias +
        q0.x * wc[0]  + q0.y * wc[1]  + q0.z * wc[2]  + q0.w * wc[3] +
        q1.x * wc[4]  + q1.y * wc[5]  + q1.z * wc[6]  + q1.w * wc[7] +
        q2.x * wc[8]  + q2.y * wc[9]  + q2.z * wc[10] + q2.w * wc[11] +
        q3.x * wc[12] + q3.y * wc[13] + q3.z * wc[14] + q3.w * wc[15];
      float m  = fmaxf(hv0 + ml, 0.f) + EPS_MSG;
      float ex = __expf(m);
      den += ex;
      num += ex * m;
    }
  }
  if (lane < 48)
    out[(size_t)node * 48 + lane] = hself + num / (den + 1e-16f);
}

// ---- GENConv aggregation d=32: half-wave/node, pipelined --------------------
__global__ void k_agg32(const u32* __restrict__ rowptr, const int2* __restrict__ csr,
                        const float* __restrict__ ea,
                        const float* __restrict__ we, const float* __restrict__ be,
                        const float* __restrict__ h, float* __restrict__ out, int n) {
  int c    = threadIdx.x & 31;
  int node = (blockIdx.x * blockDim.x + threadIdx.x) >> 5;
  if (node >= n) return;
  float wc[16];
#pragma unroll
  for (int k = 0; k < 16; k++) wc[k] = we[k * 32 + c];
  float bias  = be[c];
  float hself = h[(size_t)node * 32 + c];
  u32 b = rowptr[node], t = rowptr[node + 1];
  float den = 0.f, num = 0.f;
  if (b < t) {
    int2 es = csr[b];
    const float4* p = (const float4*)(ea + (size_t)es.y * 16);
    float4 p0 = p[0], p1 = p[1], p2 = p[2], p3 = p[3];
    float hv = h[(size_t)es.x * 32 + c];
    for (u32 i = b; i < t; i++) {
      float4 q0 = p0, q1 = p1, q2 = p2, q3 = p3;
      float hv0 = hv;
      if (i + 1 < t) {
        int2 es2 = csr[i + 1];
        const float4* pp = (const float4*)(ea + (size_t)es2.y * 16);
        p0 = pp[0]; p1 = pp[1]; p2 = pp[2]; p3 = pp[3];
        hv = h[(size_t)es2.x * 32 + c];
      }
      float ml = bias +
        q0.x * wc[0]  + q0.y * wc[1]  + q0.z * wc[2]  + q0.w * wc[3] +
        q1.x * wc[4]  + q1.y * wc[5]  + q1.z * wc[6]  + q1.w * wc[7] +
        q2.x * wc[8]  + q2.y * wc[9]  + q2.z * wc[10] + q2.w * wc[11] +
        q3.x * wc[12] + q3.y * wc[13] + q3.z * wc[14] + q3.w * wc[15];
      float m  = fmaxf(hv0 + ml, 0.f) + EPS_MSG;
      float ex = __expf(m);
      den += ex;
      num += ex * m;
    }
  }
  out[(size_t)node * 32 + c] = hself + num / (den + 1e-16f);
}

// ---- zt = X@W1 + B1 (split panels) + per-block BN-stat partials -------------
template<int D>
__global__ void k_ztstats(const float* __restrict__ X, const float* __restrict__ W,
                          const float* __restrict__ B, float* __restrict__ Z1,
                          float* __restrict__ Z2, float* __restrict__ partial, int n) {
  __shared__ float Wl[D * 2 * D];
  __shared__ float Bl[2 * D];
  __shared__ float red[4][4 * D];
  for (int t = threadIdx.x; t < D * 2 * D; t += blockDim.x) Wl[t] = W[t];
  for (int t = threadIdx.x; t < 2 * D; t += blockDim.x) Bl[t] = B[t];
  __syncthreads();
  int i = blockIdx.x * blockDim.x + threadIdx.x;
  bool act = (i < n);
  float acc[2 * D];
#pragma unroll
  for (int c = 0; c < 2 * D; c++) acc[c] = 0.f;
  if (act) {
#pragma unroll
    for (int c = 0; c < 2 * D; c++) acc[c] = Bl[c];
    const float4* xp = (const float4*)(X + (size_t)i * D);
    for (int q = 0; q < D / 4; q++) {
      float4 v = xp[q];
#pragma unroll
      for (int c = 0; c < 2 * D; c++) acc[c] += v.x * Wl[(4 * q + 0) * 2 * D + c];
#pragma unroll
      for (int c = 0; c < 2 * D; c++) acc[c] += v.y * Wl[(4 * q + 1) * 2 * D + c];
#pragma unroll
      for (int c = 0; c < 2 * D; c++) acc[c] += v.z * Wl[(4 * q + 2) * 2 * D + c];
#pragma unroll
      for (int c = 0; c < 2 * D; c++) acc[c] += v.w * Wl[(4 * q + 3) * 2 * D + c];
    }
    float* z1 = Z1 + (size_t)i * D;
    float* z2 = Z2 + (size_t)i * D;
#pragma unroll
    for (int c = 0; c < D; c++) { z1[c] = acc[c]; z2[c] = acc[D + c]; }
  } else {
#pragma unroll
    for (int c = 0; c < 2 * D; c++) acc[c] = 0.f;
  }
  int lane = threadIdx.x & 63;
  int wv   = threadIdx.x >> 6;
#pragma unroll
  for (int c = 0; c < 2 * D; c++) {
    float v = acc[c], v2 = v * v;
#pragma unroll
    for (int o = 32; o; o >>= 1) { v += __shfl_xor(v, o); v2 += __shfl_xor(v2, o); }
    if (lane == 0) { red[wv][c] = v; red[wv][2 * D + c] = v2; }
  }
  __syncthreads();
  if (threadIdx.x < 4 * D) {
    float s = red[0][threadIdx.x] + red[1][threadIdx.x] +
              red[2][threadIdx.x] + red[3][threadIdx.x];
    partial[(size_t)blockIdx.x * 4 * D + threadIdx.x] = s;
  }
}

__global__ void k_bnfin(const float* __restrict__ partial, float* __restrict__ stats,
                        int nb, int m) {
  int c = blockIdx.x * blockDim.x + threadIdx.x;
  if (c >= m) return;
  float s = 0.f;
  for (int b = 0; b < nb; b++) s += partial[(size_t)b * m + c];
  stats[c] = s;
}

// ---- BN-normalize -> relu -> @W2+b2 -> relu -> @Ws(+Bs) -> out (O wide) -----
template<int D, int DD, int O, bool ADDBS>
__global__ void k_mlp_lin(const float* __restrict__ ztA, const float* __restrict__ ztB,
                          const float* __restrict__ stats,
                          const float* __restrict__ G, const float* __restrict__ BE,
                          const float* __restrict__ W2, const float* __restrict__ B2,
                          const float* __restrict__ Wsa, const float* __restrict__ Wsb,
                          const float* __restrict__ Bs,
                          float* __restrict__ out, float invN, int n) {
  __shared__ float Wl[DD * D];
  __shared__ float Ws[D * O];
  __shared__ float Bl[D];
  __shared__ float Bsl[O];
  __shared__ float sc[DD], sh[DD];
  for (int t = threadIdx.x; t < DD * D; t += blockDim.x) Wl[t] = W2[t];
  if (Wsb == nullptr) {
    for (int t = threadIdx.x; t < D * O; t += blockDim.x) Ws[t] = Wsa[t];
  } else {  // concat two O/2-wide weights: [Wsa | Wsb]
    for (int t = threadIdx.x; t < D * O; t += blockDim.x) {
      int k = t / O, o = t % O;
      Ws[t] = (o < O / 2) ? Wsa[k * (O / 2) + o] : Wsb[k * (O / 2) + (o - O / 2)];
    }
  }
  if (threadIdx.x < D) Bl[threadIdx.x] = B2[threadIdx.x];
  if (threadIdx.x < O) Bsl[threadIdx.x] = ADDBS ? Bs[threadIdx.x] : 0.f;
  if (threadIdx.x < DD) {
    int c   = threadIdx.x;
    float m = stats[c] * invN;
    float v = stats[DD + c] * invN - m * m;
    float s = G[c] * rsqrtf(v + BN_EPS);
    sc[c] = s; sh[c] = BE[c] - m * s;
  }
  __syncthreads();
  int i = blockIdx.x * blockDim.x + threadIdx.x;
  if (i >= n) return;
  float y[D];
#pragma unroll
  for (int c = 0; c < D; c++) y[c] = Bl[c];
  const float* a = ztA + (size_t)i * D;
  const float* b = ztB + (size_t)i * D;
  for (int k = 0; k < D; k++) {
    float z = fmaxf(a[k] * sc[k] + sh[k], 0.f);
#pragma unroll
    for (int c = 0; c < D; c++) y[c] += z * Wl[k * D + c];
  }
  for (int k = D; k < DD; k++) {
    float z = fmaxf(b[k - D] * sc[k] + sh[k], 0.f);
#pragma unroll
    for (int c = 0; c < D; c++) y[c] += z * Wl[k * D + c];
  }
  float acc[O];
#pragma unroll
  for (int o = 0; o < O; o++) acc[o] = Bsl[o];
#pragma unroll
  for (int k = 0; k < D; k++) {
    float z = fmaxf(y[k], 0.f);
#pragma unroll
    for (int o = 0; o < O; o++) acc[o] += z * Ws[k * O + o];
  }
  float* yo = out + (size_t)i * O;
#pragma unroll
  for (int o = 0; o < O; o++) yo[o] = acc[o];
}

// ---- GCN heads, CSR gather, pipelined, fused store to d_out -----------------
__global__ void k_gcn(const u32* __restrict__ rowptr, const int2* __restrict__ csr,
                      const float* __restrict__ yz, const float* __restrict__ dinv,
                      const float* __restrict__ bmu, const float* __restrict__ bls,
                      float* __restrict__ out, int n) {
  int c    = threadIdx.x & 31;
  int node = (blockIdx.x * blockDim.x + threadIdx.x) >> 5;
  if (node >= n) return;
  u32 b = rowptr[node], t = rowptr[node + 1];
  float acc = 0.f;
  if (b < t) {
    int s0 = csr[b].x;
    float yv = yz[(size_t)s0 * 32 + c];
    float dv = dinv[s0];
    for (u32 i = b; i < t; i++) {
      float yv0 = yv, dv0 = dv;
      if (i + 1 < t) {
        int s1 = csr[i + 1].x;
        yv = yz[(size_t)s1 * 32 + c];
        dv = dinv[s1];
      }
      acc += yv0 * dv0;
    }
  }
  float dv  = dinv[node];
  float val = (acc + yz[(size_t)node * 32 + c] * dv) * dv +
              ((c < 16) ? bmu[c] : bls[c - 16]);
  if (c < 16) out[(size_t)node * 16 + c] = val;
  else        out[(size_t)n * 16 + (size_t)node * 16 + (c - 16)] = val;
}

extern "C" void kernel_launch(void* const* d_in, const int* in_sizes, int n_in,
                              void* d_out, int out_size, void* d_ws, size_t ws_size,
                              hipStream_t stream) {
  const float* x      = (const float*)d_in[0];
  const int*  ei      = (const int*)d_in[1];          // int32 (2,E) rows
  const float* ea     = (const float*)d_in[2];
  const float* w_src1 = (const float*)d_in[3];  const float* b_src1 = (const float*)d_in[4];
  const float* w_edge1= (const float*)d_in[5];  const float* b_edge1= (const float*)d_in[6];
  const float* w_m1a  = (const float*)d_in[7];  const float* b_m1a  = (const float*)d_in[8];
  const float* g1     = (const float*)d_in[9];  const float* be1    = (const float*)d_in[10];
  const float* w_m1b  = (const float*)d_in[11]; const float* b_m1b  = (const float*)d_in[12];
  const float* w_src2 = (const float*)d_in[13]; const float* b_src2 = (const float*)d_in[14];
  const float* w_edge2= (const float*)d_in[15]; const float* b_edge2= (const float*)d_in[16];
  const float* w_m2a  = (const float*)d_in[17]; const float* b_m2a  = (const float*)d_in[18];
  const float* g2     = (const float*)d_in[19]; const float* be2    = (const float*)d_in[20];
  const float* w_m2b  = (const float*)d_in[21]; const float* b_m2b  = (const float*)d_in[22];
  const float* w_mu   = (const float*)d_in[23]; const float* b_mu   = (const float*)d_in[24];
  const float* w_ls   = (const float*)d_in[25]; const float* b_ls   = (const float*)d_in[26];

  const int N = in_sizes[0] / 64;
  const int E = in_sizes[1] / 2;

  const int NB  = (N + 255) / 256;
  const int EB  = (E + 255) / 256;
  const int SB1 = (N + 1023) / 1024;

  float* ws     = (float*)d_ws;
  size_t N48    = (size_t)N * 48;
  float* P0     = ws;
  float* P1     = ws + N48;
  float* P2     = ws + 2 * N48;
  float* P3     = ws + 3 * N48;
  size_t o      = 4 * N48;
  u32*  rowptr  = (u32*)(ws + o);            // N+1
  u32*  cnt     = rowptr + (N + 1);          // N
  u32*  deg     = cnt + N;                   // N
  u32*  part    = deg + N;                   // 256
  float* dinv   = (float*)(part + 256);      // N
  float* stats  = dinv + N;                  // 512
  size_t po     = o + 4 * (size_t)N + 769;
  float* partial= ws + po;                   // NB*192
  size_t co     = (po + (size_t)NB * 192 + 1) & ~(size_t)1;
  int2* csr     = (int2*)(ws + co);          // E int2

  dim3 b256(256);

  hipMemsetAsync(cnt, 0, 2 * (size_t)N * sizeof(u32), stream);

  // CSR build
  k_deg<<<EB, b256, 0, stream>>>(ei, deg, E);
  k_scan1<<<SB1, b256, 0, stream>>>(deg, rowptr, part, N);
  k_scan2<<<1, 64, 0, stream>>>(part, SB1);
  k_scan3<<<NB, b256, 0, stream>>>(rowptr, part, N, E);
  k_slots<<<EB, b256, 0, stream>>>(ei, rowptr, cnt, csr, E);
  k_dinv<<<NB, b256, 0, stream>>>(deg, dinv, N);

  // ---- GENConv 1 (64 -> 48) ----
  k_lin<64, 48><<<NB, b256, 0, stream>>>(x, w_src1, b_src1, P0, 48, N);
  k_agg48<<<(N * 64 + 255) / 256, b256, 0, stream>>>(rowptr, csr, ea,
                                                     w_edge1, b_edge1, P0, P3, N);
  k_ztstats<48><<<NB, b256, 0, stream>>>(P3, w_m1a, b_m1a, P1, P2, partial, N);
  k_bnfin<<<1, 256, 0, stream>>>(partial, stats, NB, 192);
  k_mlp_lin<48, 96, 32, true><<<NB, b256, 0, stream>>>(P1, P2, stats, g1, be1,
                                                       w_m1b, b_m1b, w_src2, nullptr,
                                                       b_src2, P0, 1.0f / (float)N, N);

  // ---- GENConv 2 (48 -> 32) ----
  k_agg32<<<(N * 32 + 255) / 256, b256, 0, stream>>>(rowptr, csr, ea,
                                                     w_edge2, b_edge2, P0, P3, N);
  k_ztstats<32><<<NB, b256, 0, stream>>>(P3, w_m2a, b_m2a, P1, P2, partial, N);
  k_bnfin<<<1, 256, 0, stream>>>(partial, stats + 256, NB, 128);
  k_mlp_lin<32, 64, 32, false><<<NB, b256, 0, stream>>>(P1, P2, stats + 256, g2, be2,
                                                        w_m2b, b_m2b, w_mu, w_ls,
                                                        nullptr, P0, 1.0f / (float)N, N);

  // ---- GCN heads (fused) ----
  k_gcn<<<(N * 32 + 255) / 256, b256, 0, stream>>>(rowptr, csr, P0, dinv,
                                                   b_mu, b_ls, (float*)d_out, N);
}

// Round 10
// 1071.347 us; speedup vs baseline: 1.5452x; 1.0815x over previous
//
#include <hip/hip_runtime.h>
#include <hip/hip_bf16.h>

typedef unsigned int u32;

#define EPS_MSG 1e-7f
#define BN_EPS  1e-5f

// ---- small linear: Y[i*ldY + c] = X[i,:]·W[:,c] + B[c] ----------------------
template<int I, int O>
__global__ void k_lin(const float* __restrict__ X, const float* __restrict__ W,
                      const float* __restrict__ B, float* __restrict__ Y,
                      int ldY, int n) {
  __shared__ float Wl[I * O];
  __shared__ float Bl[O];
  for (int t = threadIdx.x; t < I * O; t += blockDim.x) Wl[t] = W[t];
  if (threadIdx.x < O) Bl[threadIdx.x] = B[threadIdx.x];
  __syncthreads();
  int i = blockIdx.x * blockDim.x + threadIdx.x;
  if (i >= n) return;
  float acc[O];
#pragma unroll
  for (int c = 0; c < O; c++) acc[c] = Bl[c];
  const float4* xp = (const float4*)(X + (size_t)i * I);
  for (int q = 0; q < I / 4; q++) {
    float4 v = xp[q];
#pragma unroll
    for (int c = 0; c < O; c++) acc[c] += v.x * Wl[(4 * q + 0) * O + c];
#pragma unroll
    for (int c = 0; c < O; c++) acc[c] += v.y * Wl[(4 * q + 1) * O + c];
#pragma unroll
    for (int c = 0; c < O; c++) acc[c] += v.z * Wl[(4 * q + 2) * O + c];
#pragma unroll
    for (int c = 0; c < O; c++) acc[c] += v.w * Wl[(4 * q + 3) * O + c];
  }
  float* y = Y + (size_t)i * ldY;
#pragma unroll
  for (int c = 0; c < O; c++) y[c] = acc[c];
}

// ---- CSR construction -------------------------------------------------------
__global__ void k_deg(const int* __restrict__ ei, u32* __restrict__ deg, int E) {
  int e = blockIdx.x * blockDim.x + threadIdx.x;
  if (e < E) atomicAdd(&deg[ei[E + e]], 1u);
}

__global__ void k_scan1(const u32* __restrict__ deg, u32* __restrict__ excl,
                        u32* __restrict__ part, int n) {
  __shared__ u32 sm[256];
  int t = threadIdx.x;
  int base = blockIdx.x * 1024 + t * 4;
  u32 v0 = (base + 0 < n) ? deg[base + 0] : 0u;
  u32 v1 = (base + 1 < n) ? deg[base + 1] : 0u;
  u32 v2 = (base + 2 < n) ? deg[base + 2] : 0u;
  u32 v3 = (base + 3 < n) ? deg[base + 3] : 0u;
  u32 tsum = v0 + v1 + v2 + v3;
  sm[t] = tsum;
  __syncthreads();
  for (int o = 1; o < 256; o <<= 1) {
    u32 v = (t >= o) ? sm[t - o] : 0u;
    __syncthreads();
    sm[t] += v;
    __syncthreads();
  }
  u32 tex = sm[t] - tsum;
  if (t == 255) part[blockIdx.x] = sm[255];
  if (base + 0 < n) excl[base + 0] = tex;
  if (base + 1 < n) excl[base + 1] = tex + v0;
  if (base + 2 < n) excl[base + 2] = tex + v0 + v1;
  if (base + 3 < n) excl[base + 3] = tex + v0 + v1 + v2;
}

__global__ void k_scan2(u32* __restrict__ part, int nb) {
  if (threadIdx.x == 0) {
    u32 acc = 0;
    for (int i = 0; i < nb; i++) { u32 v = part[i]; part[i] = acc; acc += v; }
  }
}

__global__ void k_scan3(u32* __restrict__ rowptr, const u32* __restrict__ part,
                        int n, int E) {
  int i = blockIdx.x * blockDim.x + threadIdx.x;
  if (i < n) rowptr[i] += part[i >> 10];
  if (i == 0) rowptr[n] = (u32)E;
}

__global__ void k_slots(const int* __restrict__ ei, const u32* __restrict__ rowptr,
                        u32* __restrict__ cnt, int2* __restrict__ csr, int E) {
  int e = blockIdx.x * blockDim.x + threadIdx.x;
  if (e >= E) return;
  int s = ei[e], d = ei[E + e];
  u32 slot = rowptr[d] + atomicAdd(&cnt[d], 1u);
  csr[slot] = make_int2(s, e);
}

__global__ void k_dinv(const u32* __restrict__ deg, float* __restrict__ dinv, int n) {
  int i = blockIdx.x * blockDim.x + threadIdx.x;
  if (i < n) dinv[i] = rsqrtf((float)(deg[i] + 1u));
}

// ---- GENConv aggregation d=48: wave/node, 2-way independent edge unroll -----
__global__ void k_agg48(const u32* __restrict__ rowptr, const int2* __restrict__ csr,
                        const float* __restrict__ ea,
                        const float* __restrict__ we, const float* __restrict__ be,
                        const float* __restrict__ h, float* __restrict__ out, int n) {
  int lane = threadIdx.x & 63;
  int node = (blockIdx.x * blockDim.x + threadIdx.x) >> 6;
  if (node >= n) return;
  float wc[16];
#pragma unroll
  for (int k = 0; k < 16; k++) wc[k] = 0.f;
  float bias = 0.f;
  if (lane < 48) {
#pragma unroll
    for (int k = 0; k < 16; k++) wc[k] = we[k * 48 + lane];
    bias = be[lane];
  }
  float hself = (lane < 48) ? h[(size_t)node * 48 + lane] : 0.f;
  u32 b = rowptr[node], t = rowptr[node + 1];
  float den = 0.f, num = 0.f;
  u32 i = b;
  for (; i + 2 <= t; i += 2) {
    int2 e0 = csr[i];
    int2 e1 = csr[i + 1];
    const float4* pa = (const float4*)(ea + (size_t)e0.y * 16);
    const float4* pb = (const float4*)(ea + (size_t)e1.y * 16);
    float4 a0 = pa[0], a1 = pa[1], a2 = pa[2], a3 = pa[3];
    float4 b0 = pb[0], b1 = pb[1], b2 = pb[2], b3 = pb[3];
    float h0 = (lane < 48) ? h[(size_t)e0.x * 48 + lane] : 0.f;
    float h1 = (lane < 48) ? h[(size_t)e1.x * 48 + lane] : 0.f;
    float ml0 = bias +
      a0.x * wc[0]  + a0.y * wc[1]  + a0.z * wc[2]  + a0.w * wc[3] +
      a1.x * wc[4]  + a1.y * wc[5]  + a1.z * wc[6]  + a1.w * wc[7] +
      a2.x * wc[8]  + a2.y * wc[9]  + a2.z * wc[10] + a2.w * wc[11] +
      a3.x * wc[12] + a3.y * wc[13] + a3.z * wc[14] + a3.w * wc[15];
    float ml1 = bias +
      b0.x * wc[0]  + b0.y * wc[1]  + b0.z * wc[2]  + b0.w * wc[3] +
      b1.x * wc[4]  + b1.y * wc[5]  + b1.z * wc[6]  + b1.w * wc[7] +
      b2.x * wc[8]  + b2.y * wc[9]  + b2.z * wc[10] + b2.w * wc[11] +
      b3.x * wc[12] + b3.y * wc[13] + b3.z * wc[14] + b3.w * wc[15];
    float m0  = fmaxf(h0 + ml0, 0.f) + EPS_MSG;
    float m1  = fmaxf(h1 + ml1, 0.f) + EPS_MSG;
    float ex0 = __expf(m0);
    float ex1 = __expf(m1);
    den += ex0 + ex1;
    num += ex0 * m0 + ex1 * m1;
  }
  if (i < t) {
    int2 e0 = csr[i];
    const float4* pa = (const float4*)(ea + (size_t)e0.y * 16);
    float4 a0 = pa[0], a1 = pa[1], a2 = pa[2], a3 = pa[3];
    float h0 = (lane < 48) ? h[(size_t)e0.x * 48 + lane] : 0.f;
    float ml0 = bias +
      a0.x * wc[0]  + a0.y * wc[1]  + a0.z * wc[2]  + a0.w * wc[3] +
      a1.x * wc[4]  + a1.y * wc[5]  + a1.z * wc[6]  + a1.w * wc[7] +
      a2.x * wc[8]  + a2.y * wc[9]  + a2.z * wc[10] + a2.w * wc[11] +
      a3.x * wc[12] + a3.y * wc[13] + a3.z * wc[14] + a3.w * wc[15];
    float m0  = fmaxf(h0 + ml0, 0.f) + EPS_MSG;
    float ex0 = __expf(m0);
    den += ex0;
    num += ex0 * m0;
  }
  if (lane < 48)
    out[(size_t)node * 48 + lane] = hself + num / (den + 1e-16f);
}

// ---- GENConv aggregation d=32: half-wave/node, 2-way unroll -----------------
__global__ void k_agg32(const u32* __restrict__ rowptr, const int2* __restrict__ csr,
                        const float* __restrict__ ea,
                        const float* __restrict__ we, const float* __restrict__ be,
                        const float* __restrict__ h, float* __restrict__ out, int n) {
  int c    = threadIdx.x & 31;
  int node = (blockIdx.x * blockDim.x + threadIdx.x) >> 5;
  if (node >= n) return;
  float wc[16];
#pragma unroll
  for (int k = 0; k < 16; k++) wc[k] = we[k * 32 + c];
  float bias  = be[c];
  float hself = h[(size_t)node * 32 + c];
  u32 b = rowptr[node], t = rowptr[node + 1];
  float den = 0.f, num = 0.f;
  u32 i = b;
  for (; i + 2 <= t; i += 2) {
    int2 e0 = csr[i];
    int2 e1 = csr[i + 1];
    const float4* pa = (const float4*)(ea + (size_t)e0.y * 16);
    const float4* pb = (const float4*)(ea + (size_t)e1.y * 16);
    float4 a0 = pa[0], a1 = pa[1], a2 = pa[2], a3 = pa[3];
    float4 b0 = pb[0], b1 = pb[1], b2 = pb[2], b3 = pb[3];
    float h0 = h[(size_t)e0.x * 32 + c];
    float h1 = h[(size_t)e1.x * 32 + c];
    float ml0 = bias +
      a0.x * wc[0]  + a0.y * wc[1]  + a0.z * wc[2]  + a0.w * wc[3] +
      a1.x * wc[4]  + a1.y * wc[5]  + a1.z * wc[6]  + a1.w * wc[7] +
      a2.x * wc[8]  + a2.y * wc[9]  + a2.z * wc[10] + a2.w * wc[11] +
      a3.x * wc[12] + a3.y * wc[13] + a3.z * wc[14] + a3.w * wc[15];
    float ml1 = bias +
      b0.x * wc[0]  + b0.y * wc[1]  + b0.z * wc[2]  + b0.w * wc[3] +
      b1.x * wc[4]  + b1.y * wc[5]  + b1.z * wc[6]  + b1.w * wc[7] +
      b2.x * wc[8]  + b2.y * wc[9]  + b2.z * wc[10] + b2.w * wc[11] +
      b3.x * wc[12] + b3.y * wc[13] + b3.z * wc[14] + b3.w * wc[15];
    float m0  = fmaxf(h0 + ml0, 0.f) + EPS_MSG;
    float m1  = fmaxf(h1 + ml1, 0.f) + EPS_MSG;
    float ex0 = __expf(m0);
    float ex1 = __expf(m1);
    den += ex0 + ex1;
    num += ex0 * m0 + ex1 * m1;
  }
  if (i < t) {
    int2 e0 = csr[i];
    const float4* pa = (const float4*)(ea + (size_t)e0.y * 16);
    float4 a0 = pa[0], a1 = pa[1], a2 = pa[2], a3 = pa[3];
    float h0 = h[(size_t)e0.x * 32 + c];
    float ml0 = bias +
      a0.x * wc[0]  + a0.y * wc[1]  + a0.z * wc[2]  + a0.w * wc[3] +
      a1.x * wc[4]  + a1.y * wc[5]  + a1.z * wc[6]  + a1.w * wc[7] +
      a2.x * wc[8]  + a2.y * wc[9]  + a2.z * wc[10] + a2.w * wc[11] +
      a3.x * wc[12] + a3.y * wc[13] + a3.z * wc[14] + a3.w * wc[15];
    float m0  = fmaxf(h0 + ml0, 0.f) + EPS_MSG;
    float ex0 = __expf(m0);
    den += ex0;
    num += ex0 * m0;
  }
  out[(size_t)node * 32 + c] = hself + num / (den + 1e-16f);
}

// ---- zt = X@W1 + B1 (split panels) + per-block BN-stat partials -------------
template<int D>
__global__ void k_ztstats(const float* __restrict__ X, const float* __restrict__ W,
                          const float* __restrict__ B, float* __restrict__ Z1,
                          float* __restrict__ Z2, float* __restrict__ partial, int n) {
  __shared__ float Wl[D * 2 * D];
  __shared__ float Bl[2 * D];
  __shared__ float red[4][4 * D];
  for (int t = threadIdx.x; t < D * 2 * D; t += blockDim.x) Wl[t] = W[t];
  for (int t = threadIdx.x; t < 2 * D; t += blockDim.x) Bl[t] = B[t];
  __syncthreads();
  int i = blockIdx.x * blockDim.x + threadIdx.x;
  bool act = (i < n);
  float acc[2 * D];
#pragma unroll
  for (int c = 0; c < 2 * D; c++) acc[c] = 0.f;
  if (act) {
#pragma unroll
    for (int c = 0; c < 2 * D; c++) acc[c] = Bl[c];
    const float4* xp = (const float4*)(X + (size_t)i * D);
    for (int q = 0; q < D / 4; q++) {
      float4 v = xp[q];
#pragma unroll
      for (int c = 0; c < 2 * D; c++) acc[c] += v.x * Wl[(4 * q + 0) * 2 * D + c];
#pragma unroll
      for (int c = 0; c < 2 * D; c++) acc[c] += v.y * Wl[(4 * q + 1) * 2 * D + c];
#pragma unroll
      for (int c = 0; c < 2 * D; c++) acc[c] += v.z * Wl[(4 * q + 2) * 2 * D + c];
#pragma unroll
      for (int c = 0; c < 2 * D; c++) acc[c] += v.w * Wl[(4 * q + 3) * 2 * D + c];
    }
    float* z1 = Z1 + (size_t)i * D;
    float* z2 = Z2 + (size_t)i * D;
#pragma unroll
    for (int c = 0; c < D; c++) { z1[c] = acc[c]; z2[c] = acc[D + c]; }
  } else {
#pragma unroll
    for (int c = 0; c < 2 * D; c++) acc[c] = 0.f;
  }
  int lane = threadIdx.x & 63;
  int wv   = threadIdx.x >> 6;
#pragma unroll
  for (int c = 0; c < 2 * D; c++) {
    float v = acc[c], v2 = v * v;
#pragma unroll
    for (int o = 32; o; o >>= 1) { v += __shfl_xor(v, o); v2 += __shfl_xor(v2, o); }
    if (lane == 0) { red[wv][c] = v; red[wv][2 * D + c] = v2; }
  }
  __syncthreads();
  if (threadIdx.x < 4 * D) {
    float s = red[0][threadIdx.x] + red[1][threadIdx.x] +
              red[2][threadIdx.x] + red[3][threadIdx.x];
    partial[(size_t)blockIdx.x * 4 * D + threadIdx.x] = s;
  }
}

__global__ void k_bnfin(const float* __restrict__ partial, float* __restrict__ stats,
                        int nb, int m) {
  int c = blockIdx.x * blockDim.x + threadIdx.x;
  if (c >= m) return;
  float s = 0.f;
  for (int b = 0; b < nb; b++) s += partial[(size_t)b * m + c];
  stats[c] = s;
}

// ---- BN-normalize -> relu -> @W2+b2 -> relu -> @Ws(+Bs) -> out (O wide) -----
template<int D, int DD, int O, bool ADDBS>
__global__ void k_mlp_lin(const float* __restrict__ ztA, const float* __restrict__ ztB,
                          const float* __restrict__ stats,
                          const float* __restrict__ G, const float* __restrict__ BE,
                          const float* __restrict__ W2, const float* __restrict__ B2,
                          const float* __restrict__ Wsa, const float* __restrict__ Wsb,
                          const float* __restrict__ Bs,
                          float* __restrict__ out, float invN, int n) {
  __shared__ float Wl[DD * D];
  __shared__ float Ws[D * O];
  __shared__ float Bl[D];
  __shared__ float Bsl[O];
  __shared__ float sc[DD], sh[DD];
  for (int t = threadIdx.x; t < DD * D; t += blockDim.x) Wl[t] = W2[t];
  if (Wsb == nullptr) {
    for (int t = threadIdx.x; t < D * O; t += blockDim.x) Ws[t] = Wsa[t];
  } else {
    for (int t = threadIdx.x; t < D * O; t += blockDim.x) {
      int k = t / O, o = t % O;
      Ws[t] = (o < O / 2) ? Wsa[k * (O / 2) + o] : Wsb[k * (O / 2) + (o - O / 2)];
    }
  }
  if (threadIdx.x < D) Bl[threadIdx.x] = B2[threadIdx.x];
  if (threadIdx.x < O) Bsl[threadIdx.x] = ADDBS ? Bs[threadIdx.x] : 0.f;
  if (threadIdx.x < DD) {
    int c   = threadIdx.x;
    float m = stats[c] * invN;
    float v = stats[DD + c] * invN - m * m;
    float s = G[c] * rsqrtf(v + BN_EPS);
    sc[c] = s; sh[c] = BE[c] - m * s;
  }
  __syncthreads();
  int i = blockIdx.x * blockDim.x + threadIdx.x;
  if (i >= n) return;
  float y[D];
#pragma unroll
  for (int c = 0; c < D; c++) y[c] = Bl[c];
  const float* a = ztA + (size_t)i * D;
  const float* b = ztB + (size_t)i * D;
  for (int k = 0; k < D; k++) {
    float z = fmaxf(a[k] * sc[k] + sh[k], 0.f);
#pragma unroll
    for (int c = 0; c < D; c++) y[c] += z * Wl[k * D + c];
  }
  for (int k = D; k < DD; k++) {
    float z = fmaxf(b[k - D] * sc[k] + sh[k], 0.f);
#pragma unroll
    for (int c = 0; c < D; c++) y[c] += z * Wl[k * D + c];
  }
  float acc[O];
#pragma unroll
  for (int o = 0; o < O; o++) acc[o] = Bsl[o];
#pragma unroll
  for (int k = 0; k < D; k++) {
    float z = fmaxf(y[k], 0.f);
#pragma unroll
    for (int o = 0; o < O; o++) acc[o] += z * Ws[k * O + o];
  }
  float* yo = out + (size_t)i * O;
#pragma unroll
  for (int o = 0; o < O; o++) yo[o] = acc[o];
}

// ---- GCN heads, CSR gather, 2-way unroll, fused store to d_out --------------
__global__ void k_gcn(const u32* __restrict__ rowptr, const int2* __restrict__ csr,
                      const float* __restrict__ yz, const float* __restrict__ dinv,
                      const float* __restrict__ bmu, const float* __restrict__ bls,
                      float* __restrict__ out, int n) {
  int c    = threadIdx.x & 31;
  int node = (blockIdx.x * blockDim.x + threadIdx.x) >> 5;
  if (node >= n) return;
  u32 b = rowptr[node], t = rowptr[node + 1];
  float acc = 0.f;
  u32 i = b;
  for (; i + 2 <= t; i += 2) {
    int s0 = csr[i].x;
    int s1 = csr[i + 1].x;
    float y0 = yz[(size_t)s0 * 32 + c];
    float y1 = yz[(size_t)s1 * 32 + c];
    float d0 = dinv[s0];
    float d1 = dinv[s1];
    acc += y0 * d0 + y1 * d1;
  }
  if (i < t) {
    int s0 = csr[i].x;
    acc += yz[(size_t)s0 * 32 + c] * dinv[s0];
  }
  float dv  = dinv[node];
  float val = (acc + yz[(size_t)node * 32 + c] * dv) * dv +
              ((c < 16) ? bmu[c] : bls[c - 16]);
  if (c < 16) out[(size_t)node * 16 + c] = val;
  else        out[(size_t)n * 16 + (size_t)node * 16 + (c - 16)] = val;
}

extern "C" void kernel_launch(void* const* d_in, const int* in_sizes, int n_in,
                              void* d_out, int out_size, void* d_ws, size_t ws_size,
                              hipStream_t stream) {
  const float* x      = (const float*)d_in[0];
  const int*  ei      = (const int*)d_in[1];          // int32 (2,E) rows
  const float* ea     = (const float*)d_in[2];
  const float* w_src1 = (const float*)d_in[3];  const float* b_src1 = (const float*)d_in[4];
  const float* w_edge1= (const float*)d_in[5];  const float* b_edge1= (const float*)d_in[6];
  const float* w_m1a  = (const float*)d_in[7];  const float* b_m1a  = (const float*)d_in[8];
  const float* g1     = (const float*)d_in[9];  const float* be1    = (const float*)d_in[10];
  const float* w_m1b  = (const float*)d_in[11]; const float* b_m1b  = (const float*)d_in[12];
  const float* w_src2 = (const float*)d_in[13]; const float* b_src2 = (const float*)d_in[14];
  const float* w_edge2= (const float*)d_in[15]; const float* b_edge2= (const float*)d_in[16];
  const float* w_m2a  = (const float*)d_in[17]; const float* b_m2a  = (const float*)d_in[18];
  const float* g2     = (const float*)d_in[19]; const float* be2    = (const float*)d_in[20];
  const float* w_m2b  = (const float*)d_in[21]; const float* b_m2b  = (const float*)d_in[22];
  const float* w_mu   = (const float*)d_in[23]; const float* b_mu   = (const float*)d_in[24];
  const float* w_ls   = (const float*)d_in[25]; const float* b_ls   = (const float*)d_in[26];

  const int N = in_sizes[0] / 64;
  const int E = in_sizes[1] / 2;

  const int NB  = (N + 255) / 256;
  const int EB  = (E + 255) / 256;
  const int SB1 = (N + 1023) / 1024;

  float* ws     = (float*)d_ws;
  size_t N48    = (size_t)N * 48;
  float* P0     = ws;
  float* P1     = ws + N48;
  float* P2     = ws + 2 * N48;
  float* P3     = ws + 3 * N48;
  size_t o      = 4 * N48;
  u32*  rowptr  = (u32*)(ws + o);            // N+1
  u32*  cnt     = rowptr + (N + 1);          // N
  u32*  deg     = cnt + N;                   // N
  u32*  part    = deg + N;                   // 256
  float* dinv   = (float*)(part + 256);      // N
  float* stats  = dinv + N;                  // 512
  size_t po     = o + 4 * (size_t)N + 769;
  float* partial= ws + po;                   // NB*192
  size_t co     = (po + (size_t)NB * 192 + 1) & ~(size_t)1;
  int2* csr     = (int2*)(ws + co);          // E int2

  dim3 b256(256);

  hipMemsetAsync(cnt, 0, 2 * (size_t)N * sizeof(u32), stream);

  // CSR build
  k_deg<<<EB, b256, 0, stream>>>(ei, deg, E);
  k_scan1<<<SB1, b256, 0, stream>>>(deg, rowptr, part, N);
  k_scan2<<<1, 64, 0, stream>>>(part, SB1);
  k_scan3<<<NB, b256, 0, stream>>>(rowptr, part, N, E);
  k_slots<<<EB, b256, 0, stream>>>(ei, rowptr, cnt, csr, E);
  k_dinv<<<NB, b256, 0, stream>>>(deg, dinv, N);

  // ---- GENConv 1 (64 -> 48) ----
  k_lin<64, 48><<<NB, b256, 0, stream>>>(x, w_src1, b_src1, P0, 48, N);
  k_agg48<<<(N * 64 + 255) / 256, b256, 0, stream>>>(rowptr, csr, ea,
                                                     w_edge1, b_edge1, P0, P3, N);
  k_ztstats<48><<<NB, b256, 0, stream>>>(P3, w_m1a, b_m1a, P1, P2, partial, N);
  k_bnfin<<<1, 256, 0, stream>>>(partial, stats, NB, 192);
  k_mlp_lin<48, 96, 32, true><<<NB, b256, 0, stream>>>(P1, P2, stats, g1, be1,
                                                       w_m1b, b_m1b, w_src2, nullptr,
                                                       b_src2, P0, 1.0f / (float)N, N);

  // ---- GENConv 2 (48 -> 32) ----
  k_agg32<<<(N * 32 + 255) / 256, b256, 0, stream>>>(rowptr, csr, ea,
                                                     w_edge2, b_edge2, P0, P3, N);
  k_ztstats<32><<<NB, b256, 0, stream>>>(P3, w_m2a, b_m2a, P1, P2, partial, N);
  k_bnfin<<<1, 256, 0, stream>>>(partial, stats + 256, NB, 128);
  k_mlp_lin<32, 64, 32, false><<<NB, b256, 0, stream>>>(P1, P2, stats + 256, g2, be2,
                                                        w_m2b, b_m2b, w_mu, w_ls,
                                                        nullptr, P0, 1.0f / (float)N, N);

  // ---- GCN heads (fused) ----
  k_gcn<<<(N * 32 + 255) / 256, b256, 0, stream>>>(rowptr, csr, P0, dinv,
                                                   b_mu, b_ls, (float*)d_out, N);
}